// Round 1
// baseline (259.098 us; speedup 1.0000x reference)
//
#include <hip/hip_runtime.h>
#include <hip/hip_bf16.h>
#include <stdint.h>

// y = x @ W^T + bias ; x:(32,4096) f32, W:(11008,4096) f32, bias:(11008) f32
// Memory-bound on streaming W (180 MB). bf16 MFMA for compute headroom.

#define M 32
#define N 11008
#define K 4096
#define BN 64
#define KSPLIT 8
#define KCHUNK (K / KSPLIT)      // 512
#define BK 64
#define NSTAGES (KCHUNK / BK)    // 8
#define NTILES (N / BN)          // 172

typedef __attribute__((ext_vector_type(8))) short bf16x8;
typedef __attribute__((ext_vector_type(4))) float f32x4;

// fp32 -> bf16 round-to-nearest-even, bit math (no NaN handling; inputs are finite)
static __device__ __forceinline__ unsigned short f2bf(float f) {
    unsigned int u = __float_as_uint(f);
    u += 0x7fffu + ((u >> 16) & 1u);
    return (unsigned short)(u >> 16);
}

// ---------------------------------------------------------------------------
// Kernel 1: out[m][n] = bias[n] (overwrite poison); x -> bf16 into ws
// grid 344 x 256 covers out exactly (88064 float4); x is 32768 float4.
// ---------------------------------------------------------------------------
__global__ __launch_bounds__(256) void init_kernel(
    const float* __restrict__ x, const float* __restrict__ bias,
    float* __restrict__ out, unsigned short* __restrict__ xbf)
{
    int i = blockIdx.x * 256 + threadIdx.x;
    // bias broadcast into out
    {
        const f32x4* b4 = (const f32x4*)bias;
        ((f32x4*)out)[i] = b4[i % (N / 4)];
    }
    // x fp32 -> bf16
    if (i < (M * K / 4)) {
        f32x4 v = ((const f32x4*)x)[i];
        union { unsigned short s[4]; uint2 u; } o;
        o.s[0] = f2bf(v.x); o.s[1] = f2bf(v.y);
        o.s[2] = f2bf(v.z); o.s[3] = f2bf(v.w);
        ((uint2*)xbf)[i] = o.u;
    }
}

// ---------------------------------------------------------------------------
// Kernel 2: GEMM. One block: 64 W-rows (cols of out) x all 32 x-rows x 512 K.
// W tile staged fp32 in LDS via global_load_lds (16B), source-XOR-swizzled.
// ---------------------------------------------------------------------------
__global__ __launch_bounds__(256) void gemm_kernel(
    const float* __restrict__ W, const unsigned short* __restrict__ xbf,
    float* __restrict__ out)
{
    __shared__ float lds[BN * BK];   // 64 rows x 64 fp32 = 16 KB, row stride 256B

    const int tid  = threadIdx.x;
    const int wave = tid >> 6;
    const int lane = tid & 63;
    const int quad = lane >> 4;      // 0..3
    const int l15  = lane & 15;

    const int bx     = blockIdx.x;
    const int ksplit = bx % KSPLIT;
    const int ntile  = bx / KSPLIT;
    const int nbase  = ntile * BN;
    const int kbase  = ksplit * KCHUNK;

    f32x4 acc0 = {0.f, 0.f, 0.f, 0.f};
    f32x4 acc1 = {0.f, 0.f, 0.f, 0.f};

    // staging geometry: one wave-inst = 64 lanes x 16B = 1KB = 4 rows.
    // lane l -> row r0 + l/16, chunk c = l%16 (chunk = 16B = 4 fp32).
    // stored chunk c holds global chunk c ^ (row&15)  (bank-conflict swizzle).
    const int st_rowoff = lane >> 4;   // row within 4-row group
    const int st_chunk  = lane & 15;

    for (int s = 0; s < NSTAGES; ++s) {
        const int k0 = kbase + s * BK;

        #pragma unroll
        for (int i = 0; i < 4; ++i) {
            const int rgrp = wave * 4 + i;            // 0..15 (4-row groups)
            const int row  = rgrp * 4 + st_rowoff;    // 0..63
            const int gchunk = st_chunk ^ (row & 15); // source swizzle
            const float* gp = W + (size_t)(nbase + row) * K + k0 + gchunk * 4;
            __builtin_amdgcn_global_load_lds(
                (const __attribute__((address_space(1))) void*)gp,
                (__attribute__((address_space(3))) void*)&lds[rgrp * 256],
                16, 0, 0);
        }
        __syncthreads();

        #pragma unroll
        for (int ks = 0; ks < 2; ++ks) {
            // A fragments: A[m = l15 (+16)][k = k0 + ks*32 + quad*8 + j], bf16 row-major
            const int kk = k0 + ks * 32 + quad * 8;
            bf16x8 a0 = *(const bf16x8*)(xbf + (size_t)l15 * K + kk);
            bf16x8 a1 = *(const bf16x8*)(xbf + (size_t)(16 + l15) * K + kk);

            // B fragment: B[k = quad*8+j][n = l15] = W[nbase + row][k], row = wave*16+l15
            const int row = wave * 16 + l15;
            const int g0 = ks * 8 + quad * 2;            // global chunk of k 0..3
            const int c0 = g0 ^ (row & 15);
            const int c1 = (g0 + 1) ^ (row & 15);
            f32x4 f0 = *(const f32x4*)&lds[row * 64 + c0 * 4];
            f32x4 f1 = *(const f32x4*)&lds[row * 64 + c1 * 4];

            bf16x8 b;
            b[0] = (short)f2bf(f0.x); b[1] = (short)f2bf(f0.y);
            b[2] = (short)f2bf(f0.z); b[3] = (short)f2bf(f0.w);
            b[4] = (short)f2bf(f1.x); b[5] = (short)f2bf(f1.y);
            b[6] = (short)f2bf(f1.z); b[7] = (short)f2bf(f1.w);

            acc0 = __builtin_amdgcn_mfma_f32_16x16x32_bf16(a0, b, acc0, 0, 0, 0);
            acc1 = __builtin_amdgcn_mfma_f32_16x16x32_bf16(a1, b, acc1, 0, 0, 0);
        }
        __syncthreads();
    }

    // Epilogue: C/D layout col = lane&15, row = (lane>>4)*4 + reg
    const int n = nbase + wave * 16 + l15;
    const int mr = quad * 4;
    #pragma unroll
    for (int r = 0; r < 4; ++r) {
        atomicAdd(&out[(size_t)(mr + r) * N + n],      acc0[r]);
        atomicAdd(&out[(size_t)(16 + mr + r) * N + n], acc1[r]);
    }
}

extern "C" void kernel_launch(void* const* d_in, const int* in_sizes, int n_in,
                              void* d_out, int out_size, void* d_ws, size_t ws_size,
                              hipStream_t stream) {
    const float* x    = (const float*)d_in[0];
    const float* W    = (const float*)d_in[1];
    const float* bias = (const float*)d_in[2];
    float* out        = (float*)d_out;
    unsigned short* xbf = (unsigned short*)d_ws;   // 32*4096*2 = 256 KB

    init_kernel<<<(M * N / 4) / 256, 256, 0, stream>>>(x, bias, out, xbf);
    gemm_kernel<<<NTILES * KSPLIT, 256, 0, stream>>>(W, xbf, out);
}

// Round 2
// 254.582 us; speedup vs baseline: 1.0177x; 1.0177x over previous
//
#include <hip/hip_runtime.h>
#include <hip/hip_bf16.h>
#include <stdint.h>

// y = x @ W^T + bias ; x:(32,4096) f32, W:(11008,4096) f32, bias:(11008) f32
// HBM-bound on streaming W (180 MB, read exactly once). bf16 MFMA compute.
//
// Structure: 688 blocks, each owns 16 output cols (one 16-wide MFMA N-tile)
// over the FULL K. The 4 waves split K (1024 each), stream W straight from
// global memory to registers in B-fragment layout (8 contiguous floats per
// lane = two dwordx4), convert fp32->bf16 in-register, MFMA-accumulate, then
// cross-wave reduce via LDS. No atomics, no barriers in the K-loop, no
// global_load_lds, no out-init pass.

#define M 32
#define N 11008
#define K 4096
#define BN 16
#define WKSLICE (K / 4)          // 1024 k per wave
#define KSTEPS (WKSLICE / 32)    // 32 MFMA k-steps per wave

typedef __attribute__((ext_vector_type(8))) short bf16x8;
typedef __attribute__((ext_vector_type(4))) float f32x4;

// two fp32 -> packed bf16 pair, round-to-nearest-even (finite inputs)
static __device__ __forceinline__ unsigned int pk2bf(float f0, float f1) {
    unsigned int u0 = __float_as_uint(f0);
    unsigned int u1 = __float_as_uint(f1);
    u0 += 0x7fffu + ((u0 >> 16) & 1u);
    u1 += 0x7fffu + ((u1 >> 16) & 1u);
    return (u0 >> 16) | (u1 & 0xffff0000u);
}

// ---------------------------------------------------------------------------
// Kernel 1: x fp32 -> bf16 into ws (32*4096 elems = 32768 uint2 of 4 bf16).
// ---------------------------------------------------------------------------
__global__ __launch_bounds__(256) void cvt_kernel(
    const float* __restrict__ x, unsigned short* __restrict__ xbf)
{
    int i = blockIdx.x * 256 + threadIdx.x;          // 128 blocks x 256 = 32768
    f32x4 v = ((const f32x4*)x)[i];
    uint2 o;
    o.x = pk2bf(v.x, v.y);
    o.y = pk2bf(v.z, v.w);
    ((uint2*)xbf)[i] = o;
}

// ---------------------------------------------------------------------------
// Kernel 2: GEMM, wave-autonomous K-streaming.
// B-frag (16x16x32): lane holds B[k = quad*8 + j][n = l15] = W[nbase+l15][k]
//   -> 8 contiguous floats of one W row per lane per k-step.
// A-frag: lane holds A[m = l15 (+16)][k = quad*8 + j] from bf16 x.
// C/D: col = lane&15, row = quad*4 + reg.
// ---------------------------------------------------------------------------
__global__ __launch_bounds__(256) void gemm_kernel(
    const float* __restrict__ W, const unsigned short* __restrict__ xbf,
    const float* __restrict__ bias, float* __restrict__ out)
{
    __shared__ float red[4 * 512];   // 4 waves x (32 m x 16 n) fp32 = 8 KB

    const int tid  = threadIdx.x;
    const int wave = tid >> 6;
    const int lane = tid & 63;
    const int quad = lane >> 4;
    const int l15  = lane & 15;

    const int nbase = blockIdx.x * BN;
    const int kw    = wave * WKSLICE;

    const float*          wrow = W   + (size_t)(nbase + l15) * K + kw + quad * 8;
    const unsigned short* xa0  = xbf + (size_t)l15 * K        + kw + quad * 8;
    const unsigned short* xa1  = xa0 + (size_t)16 * K;

    f32x4 acc0 = {0.f, 0.f, 0.f, 0.f};
    f32x4 acc1 = {0.f, 0.f, 0.f, 0.f};

    #pragma unroll 4
    for (int s = 0; s < KSTEPS; ++s) {
        const int off = s * 32;
        f32x4 w0 = *(const f32x4*)(wrow + off);
        f32x4 w1 = *(const f32x4*)(wrow + off + 4);
        bf16x8 a0 = *(const bf16x8*)(xa0 + off);
        bf16x8 a1 = *(const bf16x8*)(xa1 + off);

        union { bf16x8 v; unsigned int u[4]; } b;
        b.u[0] = pk2bf(w0.x, w0.y);
        b.u[1] = pk2bf(w0.z, w0.w);
        b.u[2] = pk2bf(w1.x, w1.y);
        b.u[3] = pk2bf(w1.z, w1.w);

        acc0 = __builtin_amdgcn_mfma_f32_16x16x32_bf16(a0, b.v, acc0, 0, 0, 0);
        acc1 = __builtin_amdgcn_mfma_f32_16x16x32_bf16(a1, b.v, acc1, 0, 0, 0);
    }

    // partials -> LDS (C/D layout: row = quad*4 + r, col = l15)
    #pragma unroll
    for (int r = 0; r < 4; ++r) {
        red[wave * 512 + (quad * 4 + r) * 16 + l15]        = acc0[r];
        red[wave * 512 + (16 + quad * 4 + r) * 16 + l15]   = acc1[r];
    }
    __syncthreads();

    // 512 outputs, 256 threads x 2: sum 4 waves, add bias, store
    for (int e = tid; e < 512; e += 256) {
        float s = red[e] + red[512 + e] + red[1024 + e] + red[1536 + e];
        int m = e >> 4, n = e & 15;
        out[(size_t)m * N + nbase + n] = s + bias[nbase + n];
    }
}

extern "C" void kernel_launch(void* const* d_in, const int* in_sizes, int n_in,
                              void* d_out, int out_size, void* d_ws, size_t ws_size,
                              hipStream_t stream) {
    const float* x    = (const float*)d_in[0];
    const float* W    = (const float*)d_in[1];
    const float* bias = (const float*)d_in[2];
    float* out        = (float*)d_out;
    unsigned short* xbf = (unsigned short*)d_ws;   // 256 KB

    cvt_kernel<<<(M * K / 4) / 256, 256, 0, stream>>>(x, xbf);
    gemm_kernel<<<N / BN, 256, 0, stream>>>(W, xbf, bias, out);
}